// Round 19
// baseline (167.430 us; speedup 1.0000x reference)
//
#include <hip/hip_runtime.h>
#include <hip/hip_fp16.h>

#define CH 64
#define CAP 32        // per-node bucket row = 128B (2 lines); Poisson(12.8) P(>32) ~ 1e-6
#define SPILLMAX 4096
#define HBINS 12500   // LDS ints per hist block; 2 packed u16 counters each = 25000 nodes
#define HSPAN 25000   // nodes covered per hist block
#define SLICES 64     // 4 ranges x 64 slices = 256 hist blocks; 20000 edges/slice < 65535
#define TILE 2048     // edges per binA/binC block
#define EPT 8         // edges per thread (256 * 8 = 2048)
#define BSH 9         // 512 dsts per radix bucket
#define BKT 512

// ---------------- K1: fused binA (tiles) + outdeg hist (ranges) -------------
__global__ __launch_bounds__(256) void histA_kernel(const int* __restrict__ src,
                                                    const int* __restrict__ dst,
                                                    int* __restrict__ partial,
                                                    int* __restrict__ tileHist,
                                                    int* __restrict__ nspill,
                                                    int E, int N, int R, int NT)
{
    __shared__ int h[HBINS];
    int tid = threadIdx.x;
    int bid = blockIdx.x;
    if (bid < NT) {
        // ---- binA role ----
        if (bid == 0 && tid == 0) nspill[0] = 0;   // consumed by binD, 3 kernels later
        h[tid] = 0;
        __syncthreads();
        int e0 = bid * TILE + tid * EPT;
        if (e0 + EPT <= E) {
            const int4* dp = (const int4*)(dst + e0);
            int4 a = dp[0], b = dp[1];
            atomicAdd(&h[a.x >> BSH], 1); atomicAdd(&h[a.y >> BSH], 1);
            atomicAdd(&h[a.z >> BSH], 1); atomicAdd(&h[a.w >> BSH], 1);
            atomicAdd(&h[b.x >> BSH], 1); atomicAdd(&h[b.y >> BSH], 1);
            atomicAdd(&h[b.z >> BSH], 1); atomicAdd(&h[b.w >> BSH], 1);
        } else {
            for (int k = e0; k < E && k < e0 + EPT; ++k) atomicAdd(&h[dst[k] >> BSH], 1);
        }
        __syncthreads();
        tileHist[bid * 256 + tid] = h[tid];
    } else {
        // ---- hist role (packed u16 pairs) ----
        int hb = bid - NT;
        int r  = hb % R;
        int sl = hb / R;
        int lo = r * HSPAN;
        int hi = min(lo + HSPAN, N);
        for (int i = tid; i < HBINS; i += 256) h[i] = 0;
        __syncthreads();
        int per = (E + SLICES - 1) / SLICES;
        int sb = sl * per, se = min(sb + per, E);
        for (int e = sb + tid * 4; e < se; e += 256 * 4) {
            if (e + 4 <= se) {
                int4 v = *(const int4*)(src + e);
                if (v.x >= lo && v.x < hi) { int i0 = v.x - lo; atomicAdd(&h[i0 >> 1], 1u << ((i0 & 1) << 4)); }
                if (v.y >= lo && v.y < hi) { int i1 = v.y - lo; atomicAdd(&h[i1 >> 1], 1u << ((i1 & 1) << 4)); }
                if (v.z >= lo && v.z < hi) { int i2 = v.z - lo; atomicAdd(&h[i2 >> 1], 1u << ((i2 & 1) << 4)); }
                if (v.w >= lo && v.w < hi) { int i3 = v.w - lo; atomicAdd(&h[i3 >> 1], 1u << ((i3 & 1) << 4)); }
            } else {
                for (int k = e; k < se; ++k) {
                    int sv = src[k];
                    if (sv >= lo && sv < hi) { int ii = sv - lo; atomicAdd(&h[ii >> 1], 1u << ((ii & 1) << 4)); }
                }
            }
        }
        __syncthreads();
        int* pp = partial + (size_t)hb * HBINS;
        for (int i = tid; i < HBINS; i += 256) pp[i] = h[i];
    }
}

// ---------------- K2: fused rpscale (nodes) + binB (bucket scans) -----------
__global__ __launch_bounds__(256) void rpscaleB_kernel(const int* __restrict__ partial,
                                                       const float* __restrict__ x,
                                                       __half* __restrict__ xh,
                                                       int* __restrict__ tileHist,
                                                       int* __restrict__ totals,
                                                       int N, int R, int NT, int NPB)
{
    __shared__ float nsl[256];
    __shared__ int sm[256];
    int tid = threadIdx.x;
    int bid = blockIdx.x;
    if (bid < NPB) {
        // ---- rpscale role (sum 64 packed-u16 slices per node) ----
        int n0 = bid * 256;
        int n = n0 + tid;
        if (n < N) {
            int r = n / HSPAN;
            int idx = n - r * HSPAN;
            int word = idx >> 1;
            int sh = (idx & 1) << 4;
            int s = 0;
            #pragma unroll 8
            for (int sl = 0; sl < SLICES; ++sl)
                s += (partial[(size_t)(sl * R + r) * HBINS + word] >> sh) & 0xFFFF;
            nsl[tid] = (s > 0) ? rsqrtf((float)s) : 0.0f;
        } else {
            nsl[tid] = 0.0f;
        }
        __syncthreads();
        int sub = tid & 7;
        int nl0 = tid >> 3;
        for (int p = 0; p < 8; ++p) {
            int nl = p * 32 + nl0;
            int node = n0 + nl;
            if (node >= N) break;
            float ns = nsl[nl];
            const float4* xp = (const float4*)(x + (size_t)node * CH + sub * 8);
            float4 a = xp[0], b = xp[1];
            __half2 h0 = __floats2half2_rn(a.x * ns, a.y * ns);
            __half2 h1 = __floats2half2_rn(a.z * ns, a.w * ns);
            __half2 h2 = __floats2half2_rn(b.x * ns, b.y * ns);
            __half2 h3 = __floats2half2_rn(b.z * ns, b.w * ns);
            uint4 u;
            u.x = (unsigned)__half_as_ushort(h0.x) | ((unsigned)__half_as_ushort(h0.y) << 16);
            u.y = (unsigned)__half_as_ushort(h1.x) | ((unsigned)__half_as_ushort(h1.y) << 16);
            u.z = (unsigned)__half_as_ushort(h2.x) | ((unsigned)__half_as_ushort(h2.y) << 16);
            u.w = (unsigned)__half_as_ushort(h3.x) | ((unsigned)__half_as_ushort(h3.y) << 16);
            *(uint4*)(xh + (size_t)node * CH + sub * 8) = u;
        }
    } else {
        // ---- binB role ----
        int b = bid - NPB;
        int C = (NT + 255) / 256;
        int vals[8];
        int s = 0;
        for (int k = 0; k < C; ++k) {
            int t = tid * C + k;
            vals[k] = (t < NT) ? tileHist[t * 256 + b] : 0;
            s += vals[k];
        }
        sm[tid] = s;
        __syncthreads();
        for (int d = 1; d < 256; d <<= 1) {
            int v = (tid >= d) ? sm[tid - d] : 0;
            __syncthreads();
            sm[tid] += v;
            __syncthreads();
        }
        int off = (tid > 0) ? sm[tid - 1] : 0;
        for (int k = 0; k < C; ++k) {
            int t = tid * C + k;
            if (t < NT) { tileHist[t * 256 + b] = off; off += vals[k]; }
        }
        if (tid == 255) totals[b] = sm[255];
    }
}

// ---------------- binC: LDS-staged scatter -> coalesced burst writes --------
__global__ __launch_bounds__(256) void binC_kernel(const int* __restrict__ src,
                                                   const int* __restrict__ dst,
                                                   const int* __restrict__ tileBase,
                                                   const int* __restrict__ totals,
                                                   int* __restrict__ sorted, int E, int NB)
{
    __shared__ int sm[256];     // totals scan -> bucket bases
    __shared__ int gb[256];     // global dest base per bucket for this tile
    __shared__ int lcnt[256];   // block-local per-bucket count / rank cursor
    __shared__ int lbase[256];  // block-local exclusive offsets
    __shared__ int slotVal[TILE];
    int tid = threadIdx.x;
    int t = blockIdx.x;
    sm[tid] = (tid < NB) ? totals[tid] : 0;
    lcnt[tid] = 0;
    __syncthreads();
    for (int d = 1; d < 256; d <<= 1) {
        int v = (tid >= d) ? sm[tid - d] : 0;
        __syncthreads();
        sm[tid] += v;
        __syncthreads();
    }
    int bb = (tid > 0) ? sm[tid - 1] : 0;   // exclusive bucket base
    gb[tid] = (tid < NB) ? bb + tileBase[t * 256 + tid] : 0;
    __syncthreads();
    int e0 = t * TILE + tid * EPT;
    int s[EPT], d[EPT], rk[EPT], pb[EPT];
    int nk = 0;
    if (e0 + EPT <= E) {
        const int4* sp = (const int4*)(src + e0);
        const int4* dp = (const int4*)(dst + e0);
        int4 a = sp[0], b = sp[1], c = dp[0], f = dp[1];
        s[0]=a.x; s[1]=a.y; s[2]=a.z; s[3]=a.w; s[4]=b.x; s[5]=b.y; s[6]=b.z; s[7]=b.w;
        d[0]=c.x; d[1]=c.y; d[2]=c.z; d[3]=c.w; d[4]=f.x; d[5]=f.y; d[6]=f.z; d[7]=f.w;
        nk = EPT;
    } else {
        for (int k = 0; e0 + k < E && k < EPT; ++k) { s[k] = src[e0+k]; d[k] = dst[e0+k]; nk++; }
    }
    for (int k = 0; k < nk; ++k) {
        pb[k] = d[k] >> BSH;
        rk[k] = atomicAdd(&lcnt[pb[k]], 1);
    }
    __syncthreads();
    sm[tid] = lcnt[tid];
    __syncthreads();
    for (int dd = 1; dd < 256; dd <<= 1) {
        int v = (tid >= dd) ? sm[tid - dd] : 0;
        __syncthreads();
        sm[tid] += v;
        __syncthreads();
    }
    lbase[tid] = (tid > 0) ? sm[tid - 1] : 0;
    int total = sm[255];
    __syncthreads();
    for (int k = 0; k < nk; ++k)
        slotVal[lbase[pb[k]] + rk[k]] = (s[k] << BSH) | (d[k] & (BKT - 1));
    __syncthreads();
    for (int i = tid; i < total; i += 256) {
        int lo = 0, hi = 255;            // find largest p with lbase[p] <= i
        #pragma unroll
        for (int st = 0; st < 8; ++st) {
            int mid = (lo + hi + 1) >> 1;
            if (lbase[mid] <= i) lo = mid; else hi = mid - 1;
        }
        sorted[gb[lo] + (i - lbase[lo])] = slotVal[i];
    }
}

// ---------------- binD: bucket-local fill; totals-scan in LDS ---------------
__global__ __launch_bounds__(256) void binD_kernel(const int* __restrict__ sorted,
                                                   const int* __restrict__ totals,
                                                   int* __restrict__ bucket,
                                                   int* __restrict__ cnt,
                                                   int* __restrict__ spill,
                                                   int* __restrict__ nspill, int N, int NB)
{
    __shared__ int sm[256];
    __shared__ int lc[BKT];
    int b = blockIdx.x, tid = threadIdx.x;
    sm[tid] = (tid < NB) ? totals[tid] : 0;
    lc[tid] = 0; lc[tid + 256] = 0;
    __syncthreads();
    for (int d = 1; d < 256; d <<= 1) {
        int v = (tid >= d) ? sm[tid - d] : 0;
        __syncthreads();
        sm[tid] += v;
        __syncthreads();
    }
    int beg = (b > 0) ? sm[b - 1] : 0;
    int end = sm[b];
    int nbase = b << BSH;
    for (int i = beg + tid; i < end; i += 256) {
        int v = sorted[i];
        int sv = v >> BSH;
        int dl = v & (BKT - 1);
        int pos = atomicAdd(&lc[dl], 1);
        if (pos < CAP) {
            bucket[(size_t)(nbase + dl) * CAP + pos] = sv;
        } else {                                  // statistically never
            int sp = atomicAdd(nspill, 1);
            if (sp < SPILLMAX) { spill[2*sp] = nbase + dl; spill[2*sp+1] = sv; }
        }
    }
    __syncthreads();
    int n0 = nbase + tid;
    if (n0 < N) cnt[n0] = lc[tid];
    int n1 = nbase + 256 + tid;
    if (n1 < N) cnt[n1] = lc[256 + tid];
}

// ---------------- fused aggregate + GEMM + bias -----------------------------
// Phase 1: half-wave per node gathers & normalizes -> fp32 LDS row (no fp16 hop).
// Phase 2: in-block GEMM (thread = row x col-pair) from LDS; W/bias L1-resident.
__global__ __launch_bounds__(256) void aggemm_kernel(const __half* __restrict__ xh,
                                                     const int* __restrict__ bucket,
                                                     const int* __restrict__ cnt,
                                                     const int* __restrict__ spill,
                                                     const int* __restrict__ nspill,
                                                     const float* __restrict__ W,
                                                     const float* __restrict__ bias,
                                                     float* __restrict__ out, int N)
{
    __shared__ float accum[8][CH];   // 2 KB
    int tid = threadIdx.x;
    int hw = tid >> 5;
    int sl = tid & 31;
    int node = blockIdx.x * 8 + hw;
    if (node < N) {
        int c = cnt[node];
        int m = (c < CAP) ? c : CAP;
        const int* bp = bucket + (size_t)node * CAP;
        float ax0 = 0, ay0 = 0, ax1 = 0, ay1 = 0, ax2 = 0, ay2 = 0, ax3 = 0, ay3 = 0;
        int j = 0;
        for (; j + 8 <= m; j += 8) {                 // 8 gathers in flight
            int4 va = *(const int4*)(bp + j);
            int4 vb = *(const int4*)(bp + j + 4);
            float2 f0 = __half22float2(*(const __half2*)(xh + (size_t)va.x * CH + sl * 2));
            float2 f1 = __half22float2(*(const __half2*)(xh + (size_t)va.y * CH + sl * 2));
            float2 f2 = __half22float2(*(const __half2*)(xh + (size_t)va.z * CH + sl * 2));
            float2 f3 = __half22float2(*(const __half2*)(xh + (size_t)va.w * CH + sl * 2));
            float2 f4 = __half22float2(*(const __half2*)(xh + (size_t)vb.x * CH + sl * 2));
            float2 f5 = __half22float2(*(const __half2*)(xh + (size_t)vb.y * CH + sl * 2));
            float2 f6 = __half22float2(*(const __half2*)(xh + (size_t)vb.z * CH + sl * 2));
            float2 f7 = __half22float2(*(const __half2*)(xh + (size_t)vb.w * CH + sl * 2));
            ax0 += f0.x + f4.x; ay0 += f0.y + f4.y;
            ax1 += f1.x + f5.x; ay1 += f1.y + f5.y;
            ax2 += f2.x + f6.x; ay2 += f2.y + f6.y;
            ax3 += f3.x + f7.x; ay3 += f3.y + f7.y;
        }
        for (; j + 4 <= m; j += 4) {
            int4 va = *(const int4*)(bp + j);
            float2 f0 = __half22float2(*(const __half2*)(xh + (size_t)va.x * CH + sl * 2));
            float2 f1 = __half22float2(*(const __half2*)(xh + (size_t)va.y * CH + sl * 2));
            float2 f2 = __half22float2(*(const __half2*)(xh + (size_t)va.z * CH + sl * 2));
            float2 f3 = __half22float2(*(const __half2*)(xh + (size_t)va.w * CH + sl * 2));
            ax0 += f0.x; ay0 += f0.y;
            ax1 += f1.x; ay1 += f1.y;
            ax2 += f2.x; ay2 += f2.y;
            ax3 += f3.x; ay3 += f3.y;
        }
        for (; j < m; ++j) {
            float2 f = __half22float2(*(const __half2*)(xh + (size_t)bp[j] * CH + sl * 2));
            ax0 += f.x; ay0 += f.y;
        }
        if (c > CAP) {   // cold spill sweep
            int ns = *nspill;
            if (ns > SPILLMAX) ns = SPILLMAX;
            for (int i = 0; i < ns; ++i) {
                if (spill[2 * i] == node) {
                    float2 f = __half22float2(*(const __half2*)(xh + (size_t)spill[2 * i + 1] * CH + sl * 2));
                    ax0 += f.x; ay0 += f.y;
                }
            }
        }
        float nd = (c > 0) ? rsqrtf((float)c) : 0.0f;
        float2 rr;
        rr.x = ((ax0 + ax1) + (ax2 + ax3)) * nd;
        rr.y = ((ay0 + ay1) + (ay2 + ay3)) * nd;
        *(float2*)&accum[hw][sl * 2] = rr;           // fp32 LDS handoff
    }
    __syncthreads();
    // phase 2: out[node] = accum[r] @ W + bias ; thread = (row r, col pair cp)
    int r = tid >> 5;
    int cp = (tid & 31) * 2;
    int onode = blockIdx.x * 8 + r;
    if (onode >= N) return;
    float a0 = 0.0f, a1 = 0.0f;
    #pragma unroll 8
    for (int k = 0; k < CH; ++k) {
        float a = accum[r][k];                       // LDS broadcast across 32 lanes
        float2 w = *(const float2*)(W + k * CH + cp);  // L1-resident after 1st block
        a0 += a * w.x;
        a1 += a * w.y;
    }
    float2 b = *(const float2*)(bias + cp);
    float2 o;
    o.x = a0 + b.x;
    o.y = a1 + b.y;
    *(float2*)(out + (size_t)onode * CH + cp) = o;   // 256B contiguous per row group
}

extern "C" void kernel_launch(void* const* d_in, const int* in_sizes, int n_in,
                              void* d_out, int out_size, void* d_ws, size_t ws_size,
                              hipStream_t stream)
{
    const float* x    = (const float*)d_in[0];
    const int*   edge = (const int*)d_in[1];
    const float* W    = (const float*)d_in[2];
    const float* bias = (const float*)d_in[3];
    float* out = (float*)d_out;

    int N = in_sizes[0] / CH;   // 100000
    int E = in_sizes[1] / 2;    // 1280000
    const int* src = edge;
    const int* dst = edge + E;
    int R   = (N + HSPAN - 1) / HSPAN;        // 4
    int NT  = (E + TILE - 1) / TILE;          // 625
    int NB  = (N + BKT - 1) >> BSH;           // 196
    int NPB = (N + 255) / 256;                // 391

    // workspace (ints 4B):
    // [nspill 64][spill 2*SPILLMAX][cnt N][bucket N*CAP]
    // [partial int R*SLICES*HBINS ~12.8MB — REUSED after rpscaleB as sorted E]
    // [tileHist NT*256][totals 320][align][xh N*CH halves]
    int* nspill  = (int*)d_ws;
    int* spill   = nspill + 64;
    int* cnt     = spill + 2 * SPILLMAX;
    int* bucket  = cnt + N;
    int* partial = bucket + (size_t)N * CAP;
    int* tileHist = partial + (size_t)R * SLICES * HBINS;
    int* totals   = tileHist + NT * 256;
    int* sorted   = partial;                  // written by binC (after rpscaleB)
    size_t endoff = (char*)(totals + 320) - (char*)d_ws;
    size_t xoff = (endoff + 255) & ~(size_t)255;
    __half* xh = (__half*)((char*)d_ws + xoff);

    // K1: binA tiles (bid<NT) + packed-u16 outdeg hist (bid>=NT); zeroes nspill
    histA_kernel<<<NT + R * SLICES, 256, 0, stream>>>(src, dst, partial, tileHist,
                                                      nspill, E, N, R, NT);
    // K2: rpscale (bid<NPB) + binB bucket scans (bid>=NPB)
    rpscaleB_kernel<<<NPB + NB, 256, 0, stream>>>(partial, x, xh, tileHist, totals,
                                                  N, R, NT, NPB);
    binC_kernel<<<NT, 256, 0, stream>>>(src, dst, tileHist, totals, sorted, E, NB);
    binD_kernel<<<NB, 256, 0, stream>>>(sorted, totals, bucket, cnt, spill, nspill, N, NB);
    // fused aggregate + GEMM + bias (replaces agg_kernel + gemm_out_kernel)
    aggemm_kernel<<<(N + 7) / 8, 256, 0, stream>>>(xh, bucket, cnt, spill, nspill,
                                                   W, bias, out, N);
}

// Round 21
// 166.646 us; speedup vs baseline: 1.0047x; 1.0047x over previous
//
#include <hip/hip_runtime.h>
#include <hip/hip_fp16.h>

#define CH 64
#define CAP 32        // per-node bucket row = 128B (2 lines); Poisson(12.8) P(>32) ~ 1e-6
#define SPILLMAX 4096
#define HBINS 12500   // LDS ints per hist block; 2 packed u16 counters each = 25000 nodes
#define HSPAN 25000   // nodes covered per hist block
#define SLICES 64     // 4 ranges x 64 slices = 256 hist blocks; 20000 edges/slice < 65535
#define TILE 2048     // edges per binA/binC block
#define EPT 8         // edges per thread (256 * 8 = 2048)
#define BSH 9         // 512 dsts per radix bucket
#define BKT 512

// ---------------- K1: fused binA (tiles) + outdeg hist (ranges) -------------
__global__ __launch_bounds__(256) void histA_kernel(const int* __restrict__ src,
                                                    const int* __restrict__ dst,
                                                    int* __restrict__ partial,
                                                    int* __restrict__ tileHist,
                                                    int* __restrict__ nspill,
                                                    int E, int N, int R, int NT)
{
    __shared__ int h[HBINS];
    int tid = threadIdx.x;
    int bid = blockIdx.x;
    if (bid < NT) {
        // ---- binA role ----
        if (bid == 0 && tid == 0) nspill[0] = 0;   // consumed by binD, 3 kernels later
        h[tid] = 0;
        __syncthreads();
        int e0 = bid * TILE + tid * EPT;
        if (e0 + EPT <= E) {
            const int4* dp = (const int4*)(dst + e0);
            int4 a = dp[0], b = dp[1];
            atomicAdd(&h[a.x >> BSH], 1); atomicAdd(&h[a.y >> BSH], 1);
            atomicAdd(&h[a.z >> BSH], 1); atomicAdd(&h[a.w >> BSH], 1);
            atomicAdd(&h[b.x >> BSH], 1); atomicAdd(&h[b.y >> BSH], 1);
            atomicAdd(&h[b.z >> BSH], 1); atomicAdd(&h[b.w >> BSH], 1);
        } else {
            for (int k = e0; k < E && k < e0 + EPT; ++k) atomicAdd(&h[dst[k] >> BSH], 1);
        }
        __syncthreads();
        tileHist[bid * 256 + tid] = h[tid];
    } else {
        // ---- hist role (packed u16 pairs) ----
        int hb = bid - NT;
        int r  = hb % R;
        int sl = hb / R;
        int lo = r * HSPAN;
        int hi = min(lo + HSPAN, N);
        for (int i = tid; i < HBINS; i += 256) h[i] = 0;
        __syncthreads();
        int per = (E + SLICES - 1) / SLICES;
        int sb = sl * per, se = min(sb + per, E);
        for (int e = sb + tid * 4; e < se; e += 256 * 4) {
            if (e + 4 <= se) {
                int4 v = *(const int4*)(src + e);
                if (v.x >= lo && v.x < hi) { int i0 = v.x - lo; atomicAdd(&h[i0 >> 1], 1u << ((i0 & 1) << 4)); }
                if (v.y >= lo && v.y < hi) { int i1 = v.y - lo; atomicAdd(&h[i1 >> 1], 1u << ((i1 & 1) << 4)); }
                if (v.z >= lo && v.z < hi) { int i2 = v.z - lo; atomicAdd(&h[i2 >> 1], 1u << ((i2 & 1) << 4)); }
                if (v.w >= lo && v.w < hi) { int i3 = v.w - lo; atomicAdd(&h[i3 >> 1], 1u << ((i3 & 1) << 4)); }
            } else {
                for (int k = e; k < se; ++k) {
                    int sv = src[k];
                    if (sv >= lo && sv < hi) { int ii = sv - lo; atomicAdd(&h[ii >> 1], 1u << ((ii & 1) << 4)); }
                }
            }
        }
        __syncthreads();
        int* pp = partial + (size_t)hb * HBINS;
        for (int i = tid; i < HBINS; i += 256) pp[i] = h[i];
    }
}

// ---------------- K2: fused rpscale (nodes) + binB (bucket scans) -----------
__global__ __launch_bounds__(256) void rpscaleB_kernel(const int* __restrict__ partial,
                                                       const float* __restrict__ x,
                                                       __half* __restrict__ xh,
                                                       int* __restrict__ tileHist,
                                                       int* __restrict__ totals,
                                                       int N, int R, int NT, int NPB)
{
    __shared__ float nsl[256];
    __shared__ int sm[256];
    int tid = threadIdx.x;
    int bid = blockIdx.x;
    if (bid < NPB) {
        // ---- rpscale role (sum 64 packed-u16 slices per node) ----
        int n0 = bid * 256;
        int n = n0 + tid;
        if (n < N) {
            int r = n / HSPAN;
            int idx = n - r * HSPAN;
            int word = idx >> 1;
            int sh = (idx & 1) << 4;
            int s = 0;
            #pragma unroll 8
            for (int sl = 0; sl < SLICES; ++sl)
                s += (partial[(size_t)(sl * R + r) * HBINS + word] >> sh) & 0xFFFF;
            nsl[tid] = (s > 0) ? rsqrtf((float)s) : 0.0f;
        } else {
            nsl[tid] = 0.0f;
        }
        __syncthreads();
        int sub = tid & 7;
        int nl0 = tid >> 3;
        for (int p = 0; p < 8; ++p) {
            int nl = p * 32 + nl0;
            int node = n0 + nl;
            if (node >= N) break;
            float ns = nsl[nl];
            const float4* xp = (const float4*)(x + (size_t)node * CH + sub * 8);
            float4 a = xp[0], b = xp[1];
            __half2 h0 = __floats2half2_rn(a.x * ns, a.y * ns);
            __half2 h1 = __floats2half2_rn(a.z * ns, a.w * ns);
            __half2 h2 = __floats2half2_rn(b.x * ns, b.y * ns);
            __half2 h3 = __floats2half2_rn(b.z * ns, b.w * ns);
            uint4 u;
            u.x = (unsigned)__half_as_ushort(h0.x) | ((unsigned)__half_as_ushort(h0.y) << 16);
            u.y = (unsigned)__half_as_ushort(h1.x) | ((unsigned)__half_as_ushort(h1.y) << 16);
            u.z = (unsigned)__half_as_ushort(h2.x) | ((unsigned)__half_as_ushort(h2.y) << 16);
            u.w = (unsigned)__half_as_ushort(h3.x) | ((unsigned)__half_as_ushort(h3.y) << 16);
            *(uint4*)(xh + (size_t)node * CH + sub * 8) = u;
        }
    } else {
        // ---- binB role ----
        int b = bid - NPB;
        int C = (NT + 255) / 256;
        int vals[8];
        int s = 0;
        for (int k = 0; k < C; ++k) {
            int t = tid * C + k;
            vals[k] = (t < NT) ? tileHist[t * 256 + b] : 0;
            s += vals[k];
        }
        sm[tid] = s;
        __syncthreads();
        for (int d = 1; d < 256; d <<= 1) {
            int v = (tid >= d) ? sm[tid - d] : 0;
            __syncthreads();
            sm[tid] += v;
            __syncthreads();
        }
        int off = (tid > 0) ? sm[tid - 1] : 0;
        for (int k = 0; k < C; ++k) {
            int t = tid * C + k;
            if (t < NT) { tileHist[t * 256 + b] = off; off += vals[k]; }
        }
        if (tid == 255) totals[b] = sm[255];
    }
}

// ---------------- binC: LDS-staged scatter -> coalesced burst writes --------
__global__ __launch_bounds__(256) void binC_kernel(const int* __restrict__ src,
                                                   const int* __restrict__ dst,
                                                   const int* __restrict__ tileBase,
                                                   const int* __restrict__ totals,
                                                   int* __restrict__ sorted, int E, int NB)
{
    __shared__ int sm[256];     // totals scan -> bucket bases
    __shared__ int gb[256];     // global dest base per bucket for this tile
    __shared__ int lcnt[256];   // block-local per-bucket count / rank cursor
    __shared__ int lbase[256];  // block-local exclusive offsets
    __shared__ int slotVal[TILE];
    int tid = threadIdx.x;
    int t = blockIdx.x;
    sm[tid] = (tid < NB) ? totals[tid] : 0;
    lcnt[tid] = 0;
    __syncthreads();
    for (int d = 1; d < 256; d <<= 1) {
        int v = (tid >= d) ? sm[tid - d] : 0;
        __syncthreads();
        sm[tid] += v;
        __syncthreads();
    }
    int bb = (tid > 0) ? sm[tid - 1] : 0;   // exclusive bucket base
    gb[tid] = (tid < NB) ? bb + tileBase[t * 256 + tid] : 0;
    __syncthreads();
    int e0 = t * TILE + tid * EPT;
    int s[EPT], d[EPT], rk[EPT], pb[EPT];
    int nk = 0;
    if (e0 + EPT <= E) {
        const int4* sp = (const int4*)(src + e0);
        const int4* dp = (const int4*)(dst + e0);
        int4 a = sp[0], b = sp[1], c = dp[0], f = dp[1];
        s[0]=a.x; s[1]=a.y; s[2]=a.z; s[3]=a.w; s[4]=b.x; s[5]=b.y; s[6]=b.z; s[7]=b.w;
        d[0]=c.x; d[1]=c.y; d[2]=c.z; d[3]=c.w; d[4]=f.x; d[5]=f.y; d[6]=f.z; d[7]=f.w;
        nk = EPT;
    } else {
        for (int k = 0; e0 + k < E && k < EPT; ++k) { s[k] = src[e0+k]; d[k] = dst[e0+k]; nk++; }
    }
    for (int k = 0; k < nk; ++k) {
        pb[k] = d[k] >> BSH;
        rk[k] = atomicAdd(&lcnt[pb[k]], 1);
    }
    __syncthreads();
    sm[tid] = lcnt[tid];
    __syncthreads();
    for (int dd = 1; dd < 256; dd <<= 1) {
        int v = (tid >= dd) ? sm[tid - dd] : 0;
        __syncthreads();
        sm[tid] += v;
        __syncthreads();
    }
    lbase[tid] = (tid > 0) ? sm[tid - 1] : 0;
    int total = sm[255];
    __syncthreads();
    for (int k = 0; k < nk; ++k)
        slotVal[lbase[pb[k]] + rk[k]] = (s[k] << BSH) | (d[k] & (BKT - 1));
    __syncthreads();
    for (int i = tid; i < total; i += 256) {
        int lo = 0, hi = 255;            // find largest p with lbase[p] <= i
        #pragma unroll
        for (int st = 0; st < 8; ++st) {
            int mid = (lo + hi + 1) >> 1;
            if (lbase[mid] <= i) lo = mid; else hi = mid - 1;
        }
        sorted[gb[lo] + (i - lbase[lo])] = slotVal[i];
    }
}

// ---------------- binD: bucket fill + per-node SRC-SORT + coalesced flush ---
// Two 256-node halves per 512-dst bucket. Sorted lists make co-resident agg
// half-waves sweep src-space in-phase -> gather footprint fits L2.
__global__ __launch_bounds__(256) void binD_kernel(const int* __restrict__ sorted,
                                                   const int* __restrict__ totals,
                                                   int* __restrict__ bucket,
                                                   int* __restrict__ cnt,
                                                   int* __restrict__ spill,
                                                   int* __restrict__ nspill, int N, int NB)
{
    __shared__ int sm[256];
    __shared__ int lc[256];
    __shared__ int lbuf[256 * (CAP + 1)];   // +1 pad -> bank = tid (conflict-free rows)
    int b = blockIdx.x, tid = threadIdx.x;
    sm[tid] = (tid < NB) ? totals[tid] : 0;
    __syncthreads();
    for (int d = 1; d < 256; d <<= 1) {
        int v = (tid >= d) ? sm[tid - d] : 0;
        __syncthreads();
        sm[tid] += v;
        __syncthreads();
    }
    int beg = (b > 0) ? sm[b - 1] : 0;
    int end = sm[b];
    int nbase = b << BSH;
    for (int half = 0; half < 2; ++half) {
        lc[tid] = 0;
        __syncthreads();
        for (int i = beg + tid; i < end; i += 256) {
            int v = sorted[i];
            int dl = v & (BKT - 1);
            if ((dl >> 8) == half) {
                int dh = dl & 255;
                int sv = v >> BSH;
                int pos = atomicAdd(&lc[dh], 1);
                if (pos < CAP) {
                    lbuf[dh * (CAP + 1) + pos] = sv;
                } else {                          // statistically never
                    int sp = atomicAdd(nspill, 1);
                    if (sp < SPILLMAX) { spill[2*sp] = nbase + dl; spill[2*sp+1] = sv; }
                }
            }
        }
        __syncthreads();
        // per-thread insertion sort of own node's list (<=32 ints, LDS row)
        int mm = lc[tid]; if (mm > CAP) mm = CAP;
        int* L = &lbuf[tid * (CAP + 1)];
        for (int i = 1; i < mm; ++i) {
            int key = L[i];
            int j = i - 1;
            while (j >= 0 && L[j] > key) { L[j + 1] = L[j]; --j; }
            L[j + 1] = key;
        }
        // flush own row (128B contiguous per thread, coalesced across wave)
        int nodeg = nbase + half * 256 + tid;
        if (nodeg < N) {
            cnt[nodeg] = lc[tid];
            int* gB = bucket + (size_t)nodeg * CAP;
            #pragma unroll
            for (int k = 0; k < CAP; k += 4) {
                int4 w;
                w.x = L[k]; w.y = L[k + 1]; w.z = L[k + 2]; w.w = L[k + 3];
                *(int4*)(gB + k) = w;            // slots >= mm are never read (cnt guards)
            }
        }
        __syncthreads();   // protect lbuf/lc before next half reuses them
    }
}

// ---------------- aggregate: half-wave (32 lanes) per node (r16/r18 form) ---
__global__ __launch_bounds__(256) void agg_kernel(const __half* __restrict__ xh,
                                                  const int* __restrict__ bucket,
                                                  const int* __restrict__ cnt,
                                                  const int* __restrict__ spill,
                                                  const int* __restrict__ nspill,
                                                  __half* __restrict__ aggh, int N)
{
    int node = (blockIdx.x * blockDim.x + threadIdx.x) >> 5;
    int sl = threadIdx.x & 31;
    if (node >= N) return;
    int c = cnt[node];
    int m = (c < CAP) ? c : CAP;
    const int* bp = bucket + (size_t)node * CAP;
    float ax0 = 0, ay0 = 0, ax1 = 0, ay1 = 0, ax2 = 0, ay2 = 0, ax3 = 0, ay3 = 0;
    int j = 0;
    for (; j + 8 <= m; j += 8) {                 // 8 gathers in flight
        int4 va = *(const int4*)(bp + j);
        int4 vb = *(const int4*)(bp + j + 4);
        float2 f0 = __half22float2(*(const __half2*)(xh + (size_t)va.x * CH + sl * 2));
        float2 f1 = __half22float2(*(const __half2*)(xh + (size_t)va.y * CH + sl * 2));
        float2 f2 = __half22float2(*(const __half2*)(xh + (size_t)va.z * CH + sl * 2));
        float2 f3 = __half22float2(*(const __half2*)(xh + (size_t)va.w * CH + sl * 2));
        float2 f4 = __half22float2(*(const __half2*)(xh + (size_t)vb.x * CH + sl * 2));
        float2 f5 = __half22float2(*(const __half2*)(xh + (size_t)vb.y * CH + sl * 2));
        float2 f6 = __half22float2(*(const __half2*)(xh + (size_t)vb.z * CH + sl * 2));
        float2 f7 = __half22float2(*(const __half2*)(xh + (size_t)vb.w * CH + sl * 2));
        ax0 += f0.x + f4.x; ay0 += f0.y + f4.y;
        ax1 += f1.x + f5.x; ay1 += f1.y + f5.y;
        ax2 += f2.x + f6.x; ay2 += f2.y + f6.y;
        ax3 += f3.x + f7.x; ay3 += f3.y + f7.y;
    }
    for (; j + 4 <= m; j += 4) {
        int4 va = *(const int4*)(bp + j);
        float2 f0 = __half22float2(*(const __half2*)(xh + (size_t)va.x * CH + sl * 2));
        float2 f1 = __half22float2(*(const __half2*)(xh + (size_t)va.y * CH + sl * 2));
        float2 f2 = __half22float2(*(const __half2*)(xh + (size_t)va.z * CH + sl * 2));
        float2 f3 = __half22float2(*(const __half2*)(xh + (size_t)va.w * CH + sl * 2));
        ax0 += f0.x; ay0 += f0.y;
        ax1 += f1.x; ay1 += f1.y;
        ax2 += f2.x; ay2 += f2.y;
        ax3 += f3.x; ay3 += f3.y;
    }
    for (; j < m; ++j) {
        float2 f = __half22float2(*(const __half2*)(xh + (size_t)bp[j] * CH + sl * 2));
        ax0 += f.x; ay0 += f.y;
    }
    if (c > CAP) {   // cold spill sweep
        int ns = *nspill;
        if (ns > SPILLMAX) ns = SPILLMAX;
        for (int i = 0; i < ns; ++i) {
            if (spill[2 * i] == node) {
                float2 f = __half22float2(*(const __half2*)(xh + (size_t)spill[2 * i + 1] * CH + sl * 2));
                ax0 += f.x; ay0 += f.y;
            }
        }
    }
    float nd = (c > 0) ? rsqrtf((float)c) : 0.0f;
    float rx = ((ax0 + ax1) + (ax2 + ax3)) * nd;
    float ry = ((ay0 + ay1) + (ay2 + ay3)) * nd;
    *(__half2*)(aggh + (size_t)node * CH + sl * 2) = __floats2half2_rn(rx, ry);
}

// ---------------- out = aggh @ W + bias -------------------------------------
// Wave = 64 rows x one 16-ch quarter (quarter is wave-uniform -> W/bias s_load).
__global__ __launch_bounds__(256) void gemm_out_kernel(const __half* __restrict__ aggh,
                                                       const float* __restrict__ W,
                                                       const float* __restrict__ bias,
                                                       float* __restrict__ out, int N)
{
    int g = blockIdx.x * 256 + threadIdx.x;
    int waveId = __builtin_amdgcn_readfirstlane(g >> 6);   // wave-uniform by construction
    int lane = threadIdx.x & 63;
    int quarter = waveId & 3;
    int row = ((waveId >> 2) << 6) + lane;
    if (row >= N) return;
    const int cbase = quarter * 16;                         // scalar
    float acc[16];
    #pragma unroll
    for (int i = 0; i < 16; ++i) acc[i] = 0.0f;
    const __half* xp = aggh + (size_t)row * CH;
    for (int k0 = 0; k0 < CH; k0 += 8) {
        uint4 u = *(const uint4*)(xp + k0);                 // 8 halves, one 16B load
        const __half2* hp = (const __half2*)&u;
        float xk[8];
        #pragma unroll
        for (int j = 0; j < 4; ++j) {
            float2 f = __half22float2(hp[j]);
            xk[2 * j] = f.x; xk[2 * j + 1] = f.y;
        }
        #pragma unroll
        for (int kk = 0; kk < 8; ++kk) {
            const float* wrow = W + (k0 + kk) * CH + cbase; // wave-uniform -> s_load
            #pragma unroll
            for (int q = 0; q < 4; ++q) {
                float4 w = *(const float4*)(wrow + q * 4);
                acc[q * 4 + 0] += xk[kk] * w.x;
                acc[q * 4 + 1] += xk[kk] * w.y;
                acc[q * 4 + 2] += xk[kk] * w.z;
                acc[q * 4 + 3] += xk[kk] * w.w;
            }
        }
    }
    float* op = out + (size_t)row * CH + cbase;
    #pragma unroll
    for (int q = 0; q < 4; ++q) {
        float4 b = *(const float4*)(bias + cbase + q * 4);  // wave-uniform
        float4 o;
        o.x = acc[q * 4 + 0] + b.x;
        o.y = acc[q * 4 + 1] + b.y;
        o.z = acc[q * 4 + 2] + b.z;
        o.w = acc[q * 4 + 3] + b.w;
        *(float4*)(op + q * 4) = o;                          // 64B contiguous per lane
    }
}

extern "C" void kernel_launch(void* const* d_in, const int* in_sizes, int n_in,
                              void* d_out, int out_size, void* d_ws, size_t ws_size,
                              hipStream_t stream)
{
    const float* x    = (const float*)d_in[0];
    const int*   edge = (const int*)d_in[1];
    const float* W    = (const float*)d_in[2];
    const float* bias = (const float*)d_in[3];
    float* out = (float*)d_out;

    int N = in_sizes[0] / CH;   // 100000
    int E = in_sizes[1] / 2;    // 1280000
    const int* src = edge;
    const int* dst = edge + E;
    int R   = (N + HSPAN - 1) / HSPAN;        // 4
    int NT  = (E + TILE - 1) / TILE;          // 625
    int NB  = (N + BKT - 1) >> BSH;           // 196
    int NPB = (N + 255) / 256;                // 391

    // workspace (ints 4B):
    // [nspill 64][spill 2*SPILLMAX][cnt N][bucket N*CAP]
    // [partial int R*SLICES*HBINS ~12.8MB — REUSED after rpscaleB as sorted E]
    // [tileHist NT*256][totals 320][align][xh N*CH halves][align][aggh N*CH halves]
    int* nspill  = (int*)d_ws;
    int* spill   = nspill + 64;
    int* cnt     = spill + 2 * SPILLMAX;
    int* bucket  = cnt + N;
    int* partial = bucket + (size_t)N * CAP;
    int* tileHist = partial + (size_t)R * SLICES * HBINS;
    int* totals   = tileHist + NT * 256;
    int* sorted   = partial;                  // written by binC (after rpscaleB)
    size_t endoff = (char*)(totals + 320) - (char*)d_ws;
    size_t xoff = (endoff + 255) & ~(size_t)255;
    __half* xh = (__half*)((char*)d_ws + xoff);
    size_t aoff = ((xoff + (size_t)N * CH * sizeof(__half)) + 255) & ~(size_t)255;
    __half* aggh = (__half*)((char*)d_ws + aoff);

    // K1: binA tiles (bid<NT) + packed-u16 outdeg hist (bid>=NT); zeroes nspill
    histA_kernel<<<NT + R * SLICES, 256, 0, stream>>>(src, dst, partial, tileHist,
                                                      nspill, E, N, R, NT);
    // K2: rpscale (bid<NPB) + binB bucket scans (bid>=NPB)
    rpscaleB_kernel<<<NPB + NB, 256, 0, stream>>>(partial, x, xh, tileHist, totals,
                                                  N, R, NT, NPB);
    binC_kernel<<<NT, 256, 0, stream>>>(src, dst, tileHist, totals, sorted, E, NB);
    binD_kernel<<<NB, 256, 0, stream>>>(sorted, totals, bucket, cnt, spill, nspill, N, NB);
    agg_kernel<<<((size_t)N * 32 + 255) / 256, 256, 0, stream>>>(xh, bucket, cnt, spill,
                                                                 nspill, aggh, N);
    int nwaves = 4 * ((N + 63) / 64);
    gemm_out_kernel<<<(nwaves + 3) / 4, 256, 0, stream>>>(aggh, W, bias, out, N);
}

// Round 22
// 107.692 us; speedup vs baseline: 1.5547x; 1.5474x over previous
//
#include <hip/hip_runtime.h>
#include <hip/hip_fp16.h>

#define CH 64
#define CAP 32        // per-node bucket row = 128B (2 lines); Poisson(12.8) P(>32) ~ 1e-6
#define SPILLMAX 4096
#define HBINS 12500   // LDS ints per hist block; 2 packed u16 counters each = 25000 nodes
#define HSPAN 25000   // nodes covered per hist block
#define SLICES 128    // 4 ranges x 128 slices = 512 hist blocks; 10000 edges/slice < 65535
#define TILE 2048     // edges per binA/binC block
#define EPT 8         // edges per thread (256 * 8 = 2048)
#define BSH 9         // 512 dsts per radix bucket
#define BKT 512

// ---------------- K1: fused binA (tiles) + outdeg hist (ranges) -------------
// hist role: two u16 counters packed per int -> 25000 nodes/block, src read 4x not 8x.
__global__ __launch_bounds__(256) void histA_kernel(const int* __restrict__ src,
                                                    const int* __restrict__ dst,
                                                    int* __restrict__ partial,
                                                    int* __restrict__ tileHist,
                                                    int* __restrict__ nspill,
                                                    int E, int N, int R, int NT)
{
    __shared__ int h[HBINS];
    int tid = threadIdx.x;
    int bid = blockIdx.x;
    if (bid < NT) {
        // ---- binA role ----
        if (bid == 0 && tid == 0) nspill[0] = 0;   // consumed by binD, 3 kernels later
        h[tid] = 0;
        __syncthreads();
        int e0 = bid * TILE + tid * EPT;
        if (e0 + EPT <= E) {
            const int4* dp = (const int4*)(dst + e0);
            int4 a = dp[0], b = dp[1];
            atomicAdd(&h[a.x >> BSH], 1); atomicAdd(&h[a.y >> BSH], 1);
            atomicAdd(&h[a.z >> BSH], 1); atomicAdd(&h[a.w >> BSH], 1);
            atomicAdd(&h[b.x >> BSH], 1); atomicAdd(&h[b.y >> BSH], 1);
            atomicAdd(&h[b.z >> BSH], 1); atomicAdd(&h[b.w >> BSH], 1);
        } else {
            for (int k = e0; k < E && k < e0 + EPT; ++k) atomicAdd(&h[dst[k] >> BSH], 1);
        }
        __syncthreads();
        tileHist[bid * 256 + tid] = h[tid];
    } else {
        // ---- hist role (packed u16 pairs) ----
        int hb = bid - NT;
        int r  = hb % R;
        int sl = hb / R;
        int lo = r * HSPAN;
        int hi = min(lo + HSPAN, N);
        for (int i = tid; i < HBINS; i += 256) h[i] = 0;
        __syncthreads();
        int per = (E + SLICES - 1) / SLICES;
        int sb = sl * per, se = min(sb + per, E);
        for (int e = sb + tid * 4; e < se; e += 256 * 4) {
            if (e + 4 <= se) {
                int4 v = *(const int4*)(src + e);
                if (v.x >= lo && v.x < hi) { int i0 = v.x - lo; atomicAdd(&h[i0 >> 1], 1u << ((i0 & 1) << 4)); }
                if (v.y >= lo && v.y < hi) { int i1 = v.y - lo; atomicAdd(&h[i1 >> 1], 1u << ((i1 & 1) << 4)); }
                if (v.z >= lo && v.z < hi) { int i2 = v.z - lo; atomicAdd(&h[i2 >> 1], 1u << ((i2 & 1) << 4)); }
                if (v.w >= lo && v.w < hi) { int i3 = v.w - lo; atomicAdd(&h[i3 >> 1], 1u << ((i3 & 1) << 4)); }
            } else {
                for (int k = e; k < se; ++k) {
                    int sv = src[k];
                    if (sv >= lo && sv < hi) { int ii = sv - lo; atomicAdd(&h[ii >> 1], 1u << ((ii & 1) << 4)); }
                }
            }
        }
        __syncthreads();
        int* pp = partial + (size_t)hb * HBINS;
        for (int i = tid; i < HBINS; i += 256) pp[i] = h[i];
    }
}

// ---------------- K2: fused rpscale (nodes) + binB (bucket scans) -----------
__global__ __launch_bounds__(256) void rpscaleB_kernel(const int* __restrict__ partial,
                                                       const float* __restrict__ x,
                                                       __half* __restrict__ xh,
                                                       int* __restrict__ tileHist,
                                                       int* __restrict__ totals,
                                                       int N, int R, int NT, int NPB)
{
    __shared__ float nsl[256];
    __shared__ int sm[256];
    int tid = threadIdx.x;
    int bid = blockIdx.x;
    if (bid < NPB) {
        // ---- rpscale role (sum 128 packed-u16 slices per node) ----
        int n0 = bid * 256;
        int n = n0 + tid;
        if (n < N) {
            int r = n / HSPAN;
            int idx = n - r * HSPAN;
            int word = idx >> 1;
            int sh = (idx & 1) << 4;
            int s = 0;
            #pragma unroll 8
            for (int sl = 0; sl < SLICES; ++sl)
                s += (partial[(size_t)(sl * R + r) * HBINS + word] >> sh) & 0xFFFF;
            nsl[tid] = (s > 0) ? rsqrtf((float)s) : 0.0f;
        } else {
            nsl[tid] = 0.0f;
        }
        __syncthreads();
        int sub = tid & 7;
        int nl0 = tid >> 3;
        for (int p = 0; p < 8; ++p) {
            int nl = p * 32 + nl0;
            int node = n0 + nl;
            if (node >= N) break;
            float ns = nsl[nl];
            const float4* xp = (const float4*)(x + (size_t)node * CH + sub * 8);
            float4 a = xp[0], b = xp[1];
            __half2 h0 = __floats2half2_rn(a.x * ns, a.y * ns);
            __half2 h1 = __floats2half2_rn(a.z * ns, a.w * ns);
            __half2 h2 = __floats2half2_rn(b.x * ns, b.y * ns);
            __half2 h3 = __floats2half2_rn(b.z * ns, b.w * ns);
            uint4 u;
            u.x = (unsigned)__half_as_ushort(h0.x) | ((unsigned)__half_as_ushort(h0.y) << 16);
            u.y = (unsigned)__half_as_ushort(h1.x) | ((unsigned)__half_as_ushort(h1.y) << 16);
            u.z = (unsigned)__half_as_ushort(h2.x) | ((unsigned)__half_as_ushort(h2.y) << 16);
            u.w = (unsigned)__half_as_ushort(h3.x) | ((unsigned)__half_as_ushort(h3.y) << 16);
            *(uint4*)(xh + (size_t)node * CH + sub * 8) = u;
        }
    } else {
        // ---- binB role ----
        int b = bid - NPB;
        int C = (NT + 255) / 256;
        int vals[8];
        int s = 0;
        for (int k = 0; k < C; ++k) {
            int t = tid * C + k;
            vals[k] = (t < NT) ? tileHist[t * 256 + b] : 0;
            s += vals[k];
        }
        sm[tid] = s;
        __syncthreads();
        for (int d = 1; d < 256; d <<= 1) {
            int v = (tid >= d) ? sm[tid - d] : 0;
            __syncthreads();
            sm[tid] += v;
            __syncthreads();
        }
        int off = (tid > 0) ? sm[tid - 1] : 0;
        for (int k = 0; k < C; ++k) {
            int t = tid * C + k;
            if (t < NT) { tileHist[t * 256 + b] = off; off += vals[k]; }
        }
        if (tid == 255) totals[b] = sm[255];
    }
}

// ---------------- binC: LDS-staged scatter -> coalesced burst writes --------
__global__ __launch_bounds__(256) void binC_kernel(const int* __restrict__ src,
                                                   const int* __restrict__ dst,
                                                   const int* __restrict__ tileBase,
                                                   const int* __restrict__ totals,
                                                   int* __restrict__ sorted, int E, int NB)
{
    __shared__ int sm[256];     // totals scan -> bucket bases
    __shared__ int gb[256];     // global dest base per bucket for this tile
    __shared__ int lcnt[256];   // block-local per-bucket count / rank cursor
    __shared__ int lbase[256];  // block-local exclusive offsets
    __shared__ int slotVal[TILE];
    int tid = threadIdx.x;
    int t = blockIdx.x;
    sm[tid] = (tid < NB) ? totals[tid] : 0;
    lcnt[tid] = 0;
    __syncthreads();
    for (int d = 1; d < 256; d <<= 1) {
        int v = (tid >= d) ? sm[tid - d] : 0;
        __syncthreads();
        sm[tid] += v;
        __syncthreads();
    }
    int bb = (tid > 0) ? sm[tid - 1] : 0;   // exclusive bucket base
    gb[tid] = (tid < NB) ? bb + tileBase[t * 256 + tid] : 0;
    __syncthreads();
    int e0 = t * TILE + tid * EPT;
    int s[EPT], d[EPT], rk[EPT], pb[EPT];
    int nk = 0;
    if (e0 + EPT <= E) {
        const int4* sp = (const int4*)(src + e0);
        const int4* dp = (const int4*)(dst + e0);
        int4 a = sp[0], b = sp[1], c = dp[0], f = dp[1];
        s[0]=a.x; s[1]=a.y; s[2]=a.z; s[3]=a.w; s[4]=b.x; s[5]=b.y; s[6]=b.z; s[7]=b.w;
        d[0]=c.x; d[1]=c.y; d[2]=c.z; d[3]=c.w; d[4]=f.x; d[5]=f.y; d[6]=f.z; d[7]=f.w;
        nk = EPT;
    } else {
        for (int k = 0; e0 + k < E && k < EPT; ++k) { s[k] = src[e0+k]; d[k] = dst[e0+k]; nk++; }
    }
    for (int k = 0; k < nk; ++k) {
        pb[k] = d[k] >> BSH;
        rk[k] = atomicAdd(&lcnt[pb[k]], 1);
    }
    __syncthreads();
    sm[tid] = lcnt[tid];
    __syncthreads();
    for (int dd = 1; dd < 256; dd <<= 1) {
        int v = (tid >= dd) ? sm[tid - dd] : 0;
        __syncthreads();
        sm[tid] += v;
        __syncthreads();
    }
    lbase[tid] = (tid > 0) ? sm[tid - 1] : 0;
    int total = sm[255];
    __syncthreads();
    for (int k = 0; k < nk; ++k)
        slotVal[lbase[pb[k]] + rk[k]] = (s[k] << BSH) | (d[k] & (BKT - 1));
    __syncthreads();
    for (int i = tid; i < total; i += 256) {
        int lo = 0, hi = 255;            // find largest p with lbase[p] <= i
        #pragma unroll
        for (int st = 0; st < 8; ++st) {
            int mid = (lo + hi + 1) >> 1;
            if (lbase[mid] <= i) lo = mid; else hi = mid - 1;
        }
        sorted[gb[lo] + (i - lbase[lo])] = slotVal[i];
    }
}

// ---------------- binD: bucket-local fill; totals-scan in LDS ---------------
__global__ __launch_bounds__(256) void binD_kernel(const int* __restrict__ sorted,
                                                   const int* __restrict__ totals,
                                                   int* __restrict__ bucket,
                                                   int* __restrict__ cnt,
                                                   int* __restrict__ spill,
                                                   int* __restrict__ nspill, int N, int NB)
{
    __shared__ int sm[256];
    __shared__ int lc[BKT];
    int b = blockIdx.x, tid = threadIdx.x;
    sm[tid] = (tid < NB) ? totals[tid] : 0;
    lc[tid] = 0; lc[tid + 256] = 0;
    __syncthreads();
    for (int d = 1; d < 256; d <<= 1) {
        int v = (tid >= d) ? sm[tid - d] : 0;
        __syncthreads();
        sm[tid] += v;
        __syncthreads();
    }
    int beg = (b > 0) ? sm[b - 1] : 0;
    int end = sm[b];
    int nbase = b << BSH;
    for (int i = beg + tid; i < end; i += 256) {
        int v = sorted[i];
        int sv = v >> BSH;
        int dl = v & (BKT - 1);
        int pos = atomicAdd(&lc[dl], 1);
        if (pos < CAP) {
            bucket[(size_t)(nbase + dl) * CAP + pos] = sv;
        } else {                                  // statistically never
            int sp = atomicAdd(nspill, 1);
            if (sp < SPILLMAX) { spill[2*sp] = nbase + dl; spill[2*sp+1] = sv; }
        }
    }
    __syncthreads();
    int n0 = nbase + tid;
    if (n0 < N) cnt[n0] = lc[tid];
    int n1 = nbase + 256 + tid;
    if (n1 < N) cnt[n1] = lc[256 + tid];
}

// ---------------- aggregate: half-wave (32 lanes) per node ------------------
__global__ __launch_bounds__(256) void agg_kernel(const __half* __restrict__ xh,
                                                  const int* __restrict__ bucket,
                                                  const int* __restrict__ cnt,
                                                  const int* __restrict__ spill,
                                                  const int* __restrict__ nspill,
                                                  __half* __restrict__ aggh, int N)
{
    int node = (blockIdx.x * blockDim.x + threadIdx.x) >> 5;
    int sl = threadIdx.x & 31;
    if (node >= N) return;
    int c = cnt[node];
    int m = (c < CAP) ? c : CAP;
    const int* bp = bucket + (size_t)node * CAP;
    float ax0 = 0, ay0 = 0, ax1 = 0, ay1 = 0, ax2 = 0, ay2 = 0, ax3 = 0, ay3 = 0;
    int j = 0;
    for (; j + 8 <= m; j += 8) {                 // 8 gathers in flight
        int4 va = *(const int4*)(bp + j);
        int4 vb = *(const int4*)(bp + j + 4);
        float2 f0 = __half22float2(*(const __half2*)(xh + (size_t)va.x * CH + sl * 2));
        float2 f1 = __half22float2(*(const __half2*)(xh + (size_t)va.y * CH + sl * 2));
        float2 f2 = __half22float2(*(const __half2*)(xh + (size_t)va.z * CH + sl * 2));
        float2 f3 = __half22float2(*(const __half2*)(xh + (size_t)va.w * CH + sl * 2));
        float2 f4 = __half22float2(*(const __half2*)(xh + (size_t)vb.x * CH + sl * 2));
        float2 f5 = __half22float2(*(const __half2*)(xh + (size_t)vb.y * CH + sl * 2));
        float2 f6 = __half22float2(*(const __half2*)(xh + (size_t)vb.z * CH + sl * 2));
        float2 f7 = __half22float2(*(const __half2*)(xh + (size_t)vb.w * CH + sl * 2));
        ax0 += f0.x + f4.x; ay0 += f0.y + f4.y;
        ax1 += f1.x + f5.x; ay1 += f1.y + f5.y;
        ax2 += f2.x + f6.x; ay2 += f2.y + f6.y;
        ax3 += f3.x + f7.x; ay3 += f3.y + f7.y;
    }
    for (; j + 4 <= m; j += 4) {
        int4 va = *(const int4*)(bp + j);
        float2 f0 = __half22float2(*(const __half2*)(xh + (size_t)va.x * CH + sl * 2));
        float2 f1 = __half22float2(*(const __half2*)(xh + (size_t)va.y * CH + sl * 2));
        float2 f2 = __half22float2(*(const __half2*)(xh + (size_t)va.z * CH + sl * 2));
        float2 f3 = __half22float2(*(const __half2*)(xh + (size_t)va.w * CH + sl * 2));
        ax0 += f0.x; ay0 += f0.y;
        ax1 += f1.x; ay1 += f1.y;
        ax2 += f2.x; ay2 += f2.y;
        ax3 += f3.x; ay3 += f3.y;
    }
    for (; j < m; ++j) {
        float2 f = __half22float2(*(const __half2*)(xh + (size_t)bp[j] * CH + sl * 2));
        ax0 += f.x; ay0 += f.y;
    }
    if (c > CAP) {   // cold spill sweep
        int ns = *nspill;
        if (ns > SPILLMAX) ns = SPILLMAX;
        for (int i = 0; i < ns; ++i) {
            if (spill[2 * i] == node) {
                float2 f = __half22float2(*(const __half2*)(xh + (size_t)spill[2 * i + 1] * CH + sl * 2));
                ax0 += f.x; ay0 += f.y;
            }
        }
    }
    float nd = (c > 0) ? rsqrtf((float)c) : 0.0f;
    float rx = ((ax0 + ax1) + (ax2 + ax3)) * nd;
    float ry = ((ay0 + ay1) + (ay2 + ay3)) * nd;
    *(__half2*)(aggh + (size_t)node * CH + sl * 2) = __floats2half2_rn(rx, ry);
}

// ---------------- out = aggh @ W + bias -------------------------------------
// Wave = 64 rows x one 16-ch quarter (quarter is wave-uniform -> W/bias s_load).
__global__ __launch_bounds__(256) void gemm_out_kernel(const __half* __restrict__ aggh,
                                                       const float* __restrict__ W,
                                                       const float* __restrict__ bias,
                                                       float* __restrict__ out, int N)
{
    int g = blockIdx.x * 256 + threadIdx.x;
    int waveId = __builtin_amdgcn_readfirstlane(g >> 6);   // wave-uniform by construction
    int lane = threadIdx.x & 63;
    int quarter = waveId & 3;
    int row = ((waveId >> 2) << 6) + lane;
    if (row >= N) return;
    const int cbase = quarter * 16;                         // scalar
    float acc[16];
    #pragma unroll
    for (int i = 0; i < 16; ++i) acc[i] = 0.0f;
    const __half* xp = aggh + (size_t)row * CH;
    for (int k0 = 0; k0 < CH; k0 += 8) {
        uint4 u = *(const uint4*)(xp + k0);                 // 8 halves, one 16B load
        const __half2* hp = (const __half2*)&u;
        float xk[8];
        #pragma unroll
        for (int j = 0; j < 4; ++j) {
            float2 f = __half22float2(hp[j]);
            xk[2 * j] = f.x; xk[2 * j + 1] = f.y;
        }
        #pragma unroll
        for (int kk = 0; kk < 8; ++kk) {
            const float* wrow = W + (k0 + kk) * CH + cbase; // wave-uniform -> s_load
            #pragma unroll
            for (int q = 0; q < 4; ++q) {
                float4 w = *(const float4*)(wrow + q * 4);
                acc[q * 4 + 0] += xk[kk] * w.x;
                acc[q * 4 + 1] += xk[kk] * w.y;
                acc[q * 4 + 2] += xk[kk] * w.z;
                acc[q * 4 + 3] += xk[kk] * w.w;
            }
        }
    }
    float* op = out + (size_t)row * CH + cbase;
    #pragma unroll
    for (int q = 0; q < 4; ++q) {
        float4 b = *(const float4*)(bias + cbase + q * 4);  // wave-uniform
        float4 o;
        o.x = acc[q * 4 + 0] + b.x;
        o.y = acc[q * 4 + 1] + b.y;
        o.z = acc[q * 4 + 2] + b.z;
        o.w = acc[q * 4 + 3] + b.w;
        *(float4*)(op + q * 4) = o;                          // 64B contiguous per lane
    }
}

extern "C" void kernel_launch(void* const* d_in, const int* in_sizes, int n_in,
                              void* d_out, int out_size, void* d_ws, size_t ws_size,
                              hipStream_t stream)
{
    const float* x    = (const float*)d_in[0];
    const int*   edge = (const int*)d_in[1];
    const float* W    = (const float*)d_in[2];
    const float* bias = (const float*)d_in[3];
    float* out = (float*)d_out;

    int N = in_sizes[0] / CH;   // 100000
    int E = in_sizes[1] / 2;    // 1280000
    const int* src = edge;
    const int* dst = edge + E;
    int R   = (N + HSPAN - 1) / HSPAN;        // 4
    int NT  = (E + TILE - 1) / TILE;          // 625
    int NB  = (N + BKT - 1) >> BSH;           // 196
    int NPB = (N + 255) / 256;                // 391

    // workspace (ints 4B):
    // [nspill 64][spill 2*SPILLMAX][cnt N][bucket N*CAP]
    // [partial int R*SLICES*HBINS ~25.6MB — REUSED after rpscaleB as sorted E]
    // [tileHist NT*256][totals 320][align][xh N*CH halves][align][aggh N*CH halves]
    int* nspill  = (int*)d_ws;
    int* spill   = nspill + 64;
    int* cnt     = spill + 2 * SPILLMAX;
    int* bucket  = cnt + N;
    int* partial = bucket + (size_t)N * CAP;
    int* tileHist = partial + (size_t)R * SLICES * HBINS;
    int* totals   = tileHist + NT * 256;
    int* sorted   = partial;                  // written by binC (after rpscaleB)
    size_t endoff = (char*)(totals + 320) - (char*)d_ws;
    size_t xoff = (endoff + 255) & ~(size_t)255;
    __half* xh = (__half*)((char*)d_ws + xoff);
    size_t aoff = ((xoff + (size_t)N * CH * sizeof(__half)) + 255) & ~(size_t)255;
    __half* aggh = (__half*)((char*)d_ws + aoff);

    // K1: binA tiles (bid<NT) + packed-u16 outdeg hist (bid>=NT); zeroes nspill
    histA_kernel<<<NT + R * SLICES, 256, 0, stream>>>(src, dst, partial, tileHist,
                                                      nspill, E, N, R, NT);
    // K2: rpscale (bid<NPB) + binB bucket scans (bid>=NPB)
    rpscaleB_kernel<<<NPB + NB, 256, 0, stream>>>(partial, x, xh, tileHist, totals,
                                                  N, R, NT, NPB);
    binC_kernel<<<NT, 256, 0, stream>>>(src, dst, tileHist, totals, sorted, E, NB);
    binD_kernel<<<NB, 256, 0, stream>>>(sorted, totals, bucket, cnt, spill, nspill, N, NB);
    agg_kernel<<<((size_t)N * 32 + 255) / 256, 256, 0, stream>>>(xh, bucket, cnt, spill,
                                                                 nspill, aggh, N);
    int nwaves = 4 * ((N + 63) / 64);
    gemm_out_kernel<<<(nwaves + 3) / 4, 256, 0, stream>>>(aggh, W, bias, out, N);
}